// Round 5
// baseline (146.262 us; speedup 1.0000x reference)
//
#include <hip/hip_runtime.h>

#define B_  16
#define N_  2048
#define D_  64
#define QB  128     // q rows per block (main kernel)
#define KB  64      // kv rows per tile
#define NT  (N_/KB) // 32 tiles
#define NW  8       // waves per block (512 threads)
#define TILE_ELEMS (KB * D_)   // 4096 bf16 elements per tile image

typedef __attribute__((ext_vector_type(8))) short short8;
typedef __attribute__((ext_vector_type(4))) short short4v;
typedef __attribute__((ext_vector_type(4))) float f32x4;
typedef unsigned short u16_t;

// 16x16x16 bf16 MFMA: B[k][j] layout (k = g*4+e) exactly matches the QK
// C/D output layout (kv = kvt*16 + g*4 + r) -> P never leaves registers.
#if __has_builtin(__builtin_amdgcn_mfma_f32_16x16x16_bf16)
#define MFMA16(a, b, c) __builtin_amdgcn_mfma_f32_16x16x16_bf16(a, b, c, 0, 0, 0)
#define HAVE_MFMA16 1
#elif __has_builtin(__builtin_amdgcn_mfma_f32_16x16x16bf16_1k)
#define MFMA16(a, b, c) __builtin_amdgcn_mfma_f32_16x16x16bf16_1k(a, b, c, 0, 0, 0)
#define HAVE_MFMA16 1
#else
#define HAVE_MFMA16 0
#endif

static __device__ __forceinline__ unsigned cvt_pk_bf16(float lo, float hi) {
  unsigned r;
  asm("v_cvt_pk_bf16_f32 %0, %1, %2" : "=v"(r) : "v"(lo), "v"(hi));
  return r;
}
static __device__ __forceinline__ float exp2_fast(float x) {
  float r;
  asm("v_exp_f32 %0, %1" : "=v"(r) : "v"(x));
  return r;
}
static __device__ __forceinline__ void gload_lds16(const void* g, void* l) {
  __builtin_amdgcn_global_load_lds(
      (const __attribute__((address_space(1))) unsigned*)g,
      (__attribute__((address_space(3))) unsigned*)l, 16, 0, 0);
}

union U8 { unsigned u[4]; short8 s8; };
union U4 { unsigned u[2]; short4v s4; };

// ---------------------------------------------------------------------------
// Pre-pass: K,V (f32) -> bf16 tile images in the exact swizzled (V: transposed)
// layout the main kernel's LDS expects.
// ---------------------------------------------------------------------------
__global__ __launch_bounds__(256) void prep_kernel(
    const float* __restrict__ kg, const float* __restrict__ vg,
    u16_t* __restrict__ kimg, u16_t* __restrict__ vimg) {
  const int bid = blockIdx.x;
  const int isV = bid & 1;
  const int tileid = bid >> 1;
  const float* src = (isV ? vg : kg) + (size_t)tileid * TILE_ELEMS;
  u16_t* dst = (isV ? vimg : kimg) + (size_t)tileid * TILE_ELEMS;
  const int tid = threadIdx.x;

  if (!isV) {
#pragma unroll
    for (int p = 0; p < 2; ++p) {
      int c = tid + p * 256;
      int row = c >> 3, c8 = c & 7;
      const float* sp = src + row * 64 + c8 * 8;
      float4 f0 = *(const float4*)sp;
      float4 f1 = *(const float4*)(sp + 4);
      uint4 u;
      u.x = cvt_pk_bf16(f0.x, f0.y);
      u.y = cvt_pk_bf16(f0.z, f0.w);
      u.z = cvt_pk_bf16(f1.x, f1.y);
      u.w = cvt_pk_bf16(f1.z, f1.w);
      *(uint4*)&dst[(row * 64 + c8 * 8) ^ ((row & 7) << 3)] = u;
    }
  } else {
    __shared__ float Vl[64][68];
    int row = tid >> 2, q4 = (tid & 3) * 16;
    const float* sp = src + row * 64 + q4;
#pragma unroll
    for (int i = 0; i < 4; ++i)
      *(float4*)&Vl[row][q4 + i * 4] = *(const float4*)(sp + i * 4);
    __syncthreads();
#pragma unroll
    for (int p = 0; p < 2; ++p) {
      int c = tid + p * 256;
      int d = c >> 3, kc = c & 7;
      float x[8];
#pragma unroll
      for (int j = 0; j < 8; ++j) x[j] = Vl[kc * 8 + j][d];
      uint4 u;
      u.x = cvt_pk_bf16(x[0], x[1]);
      u.y = cvt_pk_bf16(x[2], x[3]);
      u.z = cvt_pk_bf16(x[4], x[5]);
      u.w = cvt_pk_bf16(x[6], x[7]);
      *(uint4*)&dst[(d * 64 + kc * 8) ^ ((d & 7) << 3)] = u;
    }
  }
}

// ---------------------------------------------------------------------------
// Main flash-attention kernel, templated on KV-split count.
// SPLIT>1: each block does NT/SPLIT tiles, writes partial (acc, m, l) to ws.
// LDS = 32 KB (Kl+Vt dbuf only; P stays in registers) -> 4 blocks/CU.
// ---------------------------------------------------------------------------
template <int SPLIT>
__global__ __launch_bounds__(512, 8) void attn_main(
    const float* __restrict__ qg, const u16_t* __restrict__ kimg,
    const u16_t* __restrict__ vimg, float* __restrict__ outg,
    float* __restrict__ pacc, float* __restrict__ pml) {
  constexpr int TS = NT / SPLIT;
  __shared__ __align__(16) u16_t Kl[2][TILE_ELEMS];
  __shared__ __align__(16) u16_t Vt[2][TILE_ELEMS];
#if !HAVE_MFMA16
  __shared__ __align__(16) u16_t Pl[NW][16 * KB];
#endif

  const int tid = threadIdx.x;
  const int w = tid >> 6, l = tid & 63;
  const int g = l >> 4, qi = l & 15;

  // bijective XCD chunk swizzle: same-batch blocks stay on one XCD's L2
  constexpr int TOT = B_ * 16 * SPLIT;
  const int bidx = blockIdx.x;
  const int logical = (bidx & 7) * (TOT / 8) + (bidx >> 3);
  const int s  = logical & (SPLIT - 1);
  const int qt = (logical / SPLIT) & 15;
  const int b  = logical / (SPLIT * 16);
  const int q0 = qt * QB + w * 16;

  // ---- Q fragments, prescaled by (1/sqrt(64))*log2(e) for exp2 softmax ----
  short8 qf[2];
  {
    const float sc = 0.18033688011112042f;  // 0.125 * log2(e)
    const float* qp = qg + ((size_t)(b * N_ + q0 + qi)) * D_;
#pragma unroll
    for (int dc = 0; dc < 2; ++dc) {
      float4 f0 = *(const float4*)(qp + dc * 32 + g * 8);
      float4 f1 = *(const float4*)(qp + dc * 32 + g * 8 + 4);
      U8 u;
      u.u[0] = cvt_pk_bf16(f0.x * sc, f0.y * sc);
      u.u[1] = cvt_pk_bf16(f0.z * sc, f0.w * sc);
      u.u[2] = cvt_pk_bf16(f1.x * sc, f1.y * sc);
      u.u[3] = cvt_pk_bf16(f1.z * sc, f1.w * sc);
      qf[dc] = u.s8;
    }
  }

  f32x4 acc[4] = {{0,0,0,0},{0,0,0,0},{0,0,0,0},{0,0,0,0}};
  float m_run = -INFINITY;
  float l_run = 0.f;

  const u16_t* kt = kimg + (size_t)b * NT * TILE_ELEMS;
  const u16_t* vt = vimg + (size_t)b * NT * TILE_ELEMS;

  auto stage = [&](int bb, int tt) {
    const u16_t* kp = kt + (size_t)tt * TILE_ELEMS + w * 512 + l * 8;
    const u16_t* vp = vt + (size_t)tt * TILE_ELEMS + w * 512 + l * 8;
    gload_lds16(kp, &Kl[bb][w * 512]);
    gload_lds16(vp, &Vt[bb][w * 512]);
  };

  const int t0 = s * TS;
  stage(0, t0);
  __syncthreads();

  for (int i = 0; i < TS; ++i) {
    const int cur = i & 1;
    if (i + 1 < TS) stage(cur ^ 1, t0 + i + 1);   // issue-early
    const u16_t* Kc = Kl[cur];
    const u16_t* Vc = Vt[cur];

    // ---- QK^T swapped: lane(g,qi) holds S[q=qi][kv=kvt*16+g*4+r] (log2 dom) ----
    f32x4 st[4];
    __builtin_amdgcn_s_setprio(1);
#pragma unroll
    for (int kvt = 0; kvt < 4; ++kvt) {
      int kvr = kvt * 16 + qi;
      int base = kvr * 64, sw = (kvr & 7) << 3;
      short8 kf0 = *(const short8*)&Kc[(base + g * 8) ^ sw];
      short8 kf1 = *(const short8*)&Kc[(base + 32 + g * 8) ^ sw];
      f32x4 z = {0, 0, 0, 0};
      z = __builtin_amdgcn_mfma_f32_16x16x32_bf16(kf0, qf[0], z, 0, 0, 0);
      z = __builtin_amdgcn_mfma_f32_16x16x32_bf16(kf1, qf[1], z, 0, 0, 0);
      st[kvt] = z;
    }
    __builtin_amdgcn_s_setprio(0);

    // ---- online softmax, exp2 domain, defer-max (THR=8) ----
    float m01 = fmaxf(fmaxf(st[0][0], st[0][1]), fmaxf(st[0][2], st[0][3]));
    float m23 = fmaxf(fmaxf(st[1][0], st[1][1]), fmaxf(st[1][2], st[1][3]));
    float m45 = fmaxf(fmaxf(st[2][0], st[2][1]), fmaxf(st[2][2], st[2][3]));
    float m67 = fmaxf(fmaxf(st[3][0], st[3][1]), fmaxf(st[3][2], st[3][3]));
    float mloc = fmaxf(fmaxf(m01, m23), fmaxf(m45, m67));
    mloc = fmaxf(mloc, __shfl_xor(mloc, 16));
    mloc = fmaxf(mloc, __shfl_xor(mloc, 32));
    if (__any(mloc > m_run + 8.0f)) {
      float mnew = fmaxf(m_run, mloc);
      float alpha = exp2_fast(m_run - mnew);
      m_run = mnew;
      l_run *= alpha;
#pragma unroll
      for (int dt = 0; dt < 4; ++dt)
#pragma unroll
        for (int r = 0; r < 4; ++r) acc[dt][r] *= alpha;
    }
    float ps = 0.f;
#pragma unroll
    for (int kvt = 0; kvt < 4; ++kvt)
#pragma unroll
      for (int r = 0; r < 4; ++r) {
        float p = exp2_fast(st[kvt][r] - m_run);
        st[kvt][r] = p;
        ps += p;
      }
    ps += __shfl_xor(ps, 16);
    ps += __shfl_xor(ps, 32);
    l_run += ps;

#if HAVE_MFMA16
    // ---- PV via 16x16x16: P packed in-register is directly the B operand.
    // B[k=g*4+e][j=qi] with step kvt -> kv = kvt*16+g*4+e == st[kvt][e]. ----
    __builtin_amdgcn_s_setprio(1);
#pragma unroll
    for (int kvt = 0; kvt < 4; ++kvt) {
      U4 pu;
      pu.u[0] = cvt_pk_bf16(st[kvt][0], st[kvt][1]);
      pu.u[1] = cvt_pk_bf16(st[kvt][2], st[kvt][3]);
      short4v pf = pu.s4;
#pragma unroll
      for (int dt = 0; dt < 4; ++dt) {
        int d = dt * 16 + qi;
        short4v vf = *(const short4v*)&Vc[(d * 64 + kvt * 16 + g * 4) ^ ((d & 7) << 3)];
        acc[dt] = MFMA16(vf, pf, acc[dt]);
      }
    }
    __builtin_amdgcn_s_setprio(0);
#else
    // ---- fallback: P via per-wave swizzled LDS + 16x16x32 PV ----
#pragma unroll
    for (int kvt = 0; kvt < 4; ++kvt) {
      unsigned u0 = cvt_pk_bf16(st[kvt][0], st[kvt][1]);
      unsigned u1 = cvt_pk_bf16(st[kvt][2], st[kvt][3]);
      int kv = kvt * 16 + g * 4;
      int sw = (qi & 7) << 3;
      *(unsigned*)&Pl[w][(qi * 64 + kv) ^ sw]     = u0;
      *(unsigned*)&Pl[w][(qi * 64 + kv + 2) ^ sw] = u1;
    }
    asm volatile("s_waitcnt lgkmcnt(0)" ::: "memory");
    __builtin_amdgcn_s_setprio(1);
#pragma unroll
    for (int kk = 0; kk < 2; ++kk) {
      short8 pf = *(const short8*)&Pl[w][(qi * 64 + kk * 32 + g * 8) ^ ((qi & 7) << 3)];
#pragma unroll
      for (int dt = 0; dt < 4; ++dt) {
        int d = dt * 16 + qi;
        short8 vf = *(const short8*)&Vc[(d * 64 + kk * 32 + g * 8) ^ ((d & 7) << 3)];
        acc[dt] = __builtin_amdgcn_mfma_f32_16x16x32_bf16(vf, pf, acc[dt], 0, 0, 0);
      }
    }
    __builtin_amdgcn_s_setprio(0);
#endif
    __syncthreads();
  }

  const int wq = w * 16 + qi;
  if constexpr (SPLIT == 1) {
    float rl = 1.0f / l_run;
    float* op = outg + ((size_t)(b * N_ + qt * QB + wq)) * D_;
#pragma unroll
    for (int dt = 0; dt < 4; ++dt) {
      float4 o;
      o.x = acc[dt][0] * rl;
      o.y = acc[dt][1] * rl;
      o.z = acc[dt][2] * rl;
      o.w = acc[dt][3] * rl;
      *(float4*)(op + dt * 16 + g * 4) = o;
    }
  } else {
    const size_t rowid = (size_t)logical * QB + wq;
    float* ap = pacc + rowid * D_;
#pragma unroll
    for (int dt = 0; dt < 4; ++dt) {
      float4 o;
      o.x = acc[dt][0]; o.y = acc[dt][1]; o.z = acc[dt][2]; o.w = acc[dt][3];
      *(float4*)(ap + dt * 16 + g * 4) = o;
    }
    if (g == 0) *(float2*)&pml[rowid * 2] = make_float2(m_run, l_run);
  }
}

// ---------------------------------------------------------------------------
// Combine: merge SPLIT partials per q-row (log2-domain flash merge).
// ---------------------------------------------------------------------------
template <int SPLIT>
__global__ __launch_bounds__(256) void combine_kernel(
    const float* __restrict__ pacc, const float* __restrict__ pml,
    float* __restrict__ outg) {
  const int fid = blockIdx.x * 256 + threadIdx.x;
  const int q = fid >> 4;
  const int c = fid & 15;
  const int b = q >> 11, rem = q & 2047;
  const int qt = rem >> 7, wq = rem & 127;
  const size_t base = ((size_t)(b * 16 + qt) * SPLIT) * QB + wq;

  float m[SPLIT], lv[SPLIT];
#pragma unroll
  for (int s2 = 0; s2 < SPLIT; ++s2) {
    float2 ml = *(const float2*)&pml[(base + (size_t)s2 * QB) * 2];
    m[s2] = ml.x; lv[s2] = ml.y;
  }
  float ms = m[0];
#pragma unroll
  for (int s2 = 1; s2 < SPLIT; ++s2) ms = fmaxf(ms, m[s2]);
  float L = 0.f, wgt[SPLIT];
#pragma unroll
  for (int s2 = 0; s2 < SPLIT; ++s2) {
    wgt[s2] = exp2_fast(m[s2] - ms);
    L += wgt[s2] * lv[s2];
  }
  float rl = 1.0f / L;

  float4 o = {0.f, 0.f, 0.f, 0.f};
#pragma unroll
  for (int s2 = 0; s2 < SPLIT; ++s2) {
    float4 a = *(const float4*)&pacc[(base + (size_t)s2 * QB) * D_ + c * 4];
    o.x += wgt[s2] * a.x;
    o.y += wgt[s2] * a.y;
    o.z += wgt[s2] * a.z;
    o.w += wgt[s2] * a.w;
  }
  o.x *= rl; o.y *= rl; o.z *= rl; o.w *= rl;
  *(float4*)&outg[(size_t)fid * 4] = o;
}

// ---------------------------------------------------------------------------
// Fallback (known-good R2 kernel) if workspace is too small.
// ---------------------------------------------------------------------------
__global__ __launch_bounds__(512, 2) void attn_fwd_fallback(
    const float* __restrict__ qg, const float* __restrict__ kg,
    const float* __restrict__ vg, float* __restrict__ outg) {
  __shared__ __align__(16) u16_t Kl[KB * D_];
  __shared__ __align__(16) u16_t Vt[D_ * KB];
  __shared__ __align__(16) u16_t Pl[NW][16 * KB];

  const int tid = threadIdx.x;
  const int w = tid >> 6, l = tid & 63;
  const int g = l >> 4, qi = l & 15;
  const int bidx = blockIdx.x;
  const int b = bidx >> 4, qt = bidx & 15;
  const int q0 = qt * QB + w * 16;

  short8 qf[2];
  {
    const float* qp = qg + ((size_t)(b * N_ + q0 + qi)) * D_;
    const float sc = 0.125f;
#pragma unroll
    for (int dc = 0; dc < 2; ++dc) {
      float4 f0 = *(const float4*)(qp + dc * 32 + g * 8);
      float4 f1 = *(const float4*)(qp + dc * 32 + g * 8 + 4);
      U8 u;
      u.u[0] = cvt_pk_bf16(f0.x * sc, f0.y * sc);
      u.u[1] = cvt_pk_bf16(f0.z * sc, f0.w * sc);
      u.u[2] = cvt_pk_bf16(f1.x * sc, f1.y * sc);
      u.u[3] = cvt_pk_bf16(f1.z * sc, f1.w * sc);
      qf[dc] = u.s8;
    }
  }

  f32x4 acc[4] = {{0,0,0,0},{0,0,0,0},{0,0,0,0},{0,0,0,0}};
  float m_run = -INFINITY, l_run = 0.f;
  const float* kbase = kg + (size_t)b * N_ * D_;
  const float* vbase = vg + (size_t)b * N_ * D_;

  for (int kv0 = 0; kv0 < N_; kv0 += KB) {
#pragma unroll
    for (int p = 0; p < 2; ++p) {
      int idx = tid + p * 512;
      int row = idx >> 4, c4 = idx & 15;
      float4 f = *(const float4*)(kbase + (size_t)(kv0 + row) * D_ + c4 * 4);
      unsigned u0 = cvt_pk_bf16(f.x, f.y);
      unsigned u1 = cvt_pk_bf16(f.z, f.w);
      int o = (row * 64 + c4 * 4) ^ ((row & 7) << 3);
      *(uint2*)&Kl[o] = make_uint2(u0, u1);
    }
    {
      int rp = tid >> 4, c4 = tid & 15;
      int row2 = rp * 2;
      const float* vp = vbase + (size_t)(kv0 + row2) * D_ + c4 * 4;
      float4 a0 = *(const float4*)vp;
      float4 a1 = *(const float4*)(vp + D_);
      float lo[4] = {a0.x, a0.y, a0.z, a0.w};
      float hi[4] = {a1.x, a1.y, a1.z, a1.w};
#pragma unroll
      for (int i = 0; i < 4; ++i) {
        int d = c4 * 4 + i;
        unsigned u = cvt_pk_bf16(lo[i], hi[i]);
        int o = (d * 64 + row2) ^ ((d & 7) << 3);
        *(unsigned*)&Vt[o] = u;
      }
    }
    __syncthreads();

    f32x4 st[4];
#pragma unroll
    for (int kvt = 0; kvt < 4; ++kvt) {
      int kvr = kvt * 16 + qi;
      int base = kvr * 64, sw = (kvr & 7) << 3;
      short8 kf0 = *(const short8*)&Kl[(base + g * 8) ^ sw];
      short8 kf1 = *(const short8*)&Kl[(base + 32 + g * 8) ^ sw];
      f32x4 z = {0, 0, 0, 0};
      z = __builtin_amdgcn_mfma_f32_16x16x32_bf16(kf0, qf[0], z, 0, 0, 0);
      z = __builtin_amdgcn_mfma_f32_16x16x32_bf16(kf1, qf[1], z, 0, 0, 0);
      st[kvt] = z;
    }

    float mloc = -INFINITY;
#pragma unroll
    for (int kvt = 0; kvt < 4; ++kvt)
#pragma unroll
      for (int r = 0; r < 4; ++r) mloc = fmaxf(mloc, st[kvt][r]);
    mloc = fmaxf(mloc, __shfl_xor(mloc, 16));
    mloc = fmaxf(mloc, __shfl_xor(mloc, 32));
    float mnew = fmaxf(m_run, mloc);
    float alpha = __expf(m_run - mnew);
    m_run = mnew;

    float ps = 0.f;
#pragma unroll
    for (int kvt = 0; kvt < 4; ++kvt)
#pragma unroll
      for (int r = 0; r < 4; ++r) {
        float p = __expf(st[kvt][r] - mnew);
        st[kvt][r] = p;
        ps += p;
      }
    ps += __shfl_xor(ps, 16);
    ps += __shfl_xor(ps, 32);
    l_run = l_run * alpha + ps;

#pragma unroll
    for (int dt = 0; dt < 4; ++dt)
#pragma unroll
      for (int r = 0; r < 4; ++r) acc[dt][r] *= alpha;

#pragma unroll
    for (int kvt = 0; kvt < 4; ++kvt) {
      unsigned u0 = cvt_pk_bf16(st[kvt][0], st[kvt][1]);
      unsigned u1 = cvt_pk_bf16(st[kvt][2], st[kvt][3]);
      int kv = kvt * 16 + g * 4;
      int sw = (qi & 7) << 3;
      *(unsigned*)&Pl[w][(qi * 64 + kv) ^ sw]     = u0;
      *(unsigned*)&Pl[w][(qi * 64 + kv + 2) ^ sw] = u1;
    }
    asm volatile("s_waitcnt lgkmcnt(0)" ::: "memory");

#pragma unroll
    for (int kk = 0; kk < 2; ++kk) {
      short8 pf = *(const short8*)&Pl[w][(qi * 64 + kk * 32 + g * 8) ^ ((qi & 7) << 3)];
#pragma unroll
      for (int dt = 0; dt < 4; ++dt) {
        int d = dt * 16 + qi;
        short8 vf = *(const short8*)&Vt[(d * 64 + kk * 32 + g * 8) ^ ((d & 7) << 3)];
        acc[dt] = __builtin_amdgcn_mfma_f32_16x16x32_bf16(vf, pf, acc[dt], 0, 0, 0);
      }
    }
    __syncthreads();
  }

  float rl = 1.0f / l_run;
  float* op = outg + ((size_t)(b * N_ + q0 + qi)) * D_;
#pragma unroll
  for (int dt = 0; dt < 4; ++dt) {
    float4 o;
    o.x = acc[dt][0] * rl;
    o.y = acc[dt][1] * rl;
    o.z = acc[dt][2] * rl;
    o.w = acc[dt][3] * rl;
    *(float4*)(op + dt * 16 + g * 4) = o;
  }
}

extern "C" void kernel_launch(void* const* d_in, const int* in_sizes, int n_in,
                              void* d_out, int out_size, void* d_ws, size_t ws_size,
                              hipStream_t stream) {
  const float* q = (const float*)d_in[0];
  const float* k = (const float*)d_in[1];
  const float* v = (const float*)d_in[2];
  float* out = (float*)d_out;

  constexpr int SPLIT = 4;
  const size_t img_elems = (size_t)B_ * N_ * D_;            // 2M bf16 per image
  const size_t img_bytes = 2 * img_elems * sizeof(u16_t);   // 8 MB (K+V)
  const size_t rows = (size_t)B_ * N_ * SPLIT;              // partial rows
  const size_t acc_bytes = rows * D_ * sizeof(float);       // 33.5 MB
  const size_t ml_bytes = rows * 2 * sizeof(float);         // 1 MB
  const size_t need_split = img_bytes + acc_bytes + ml_bytes;

  if (ws_size >= need_split) {
    u16_t* kimg = (u16_t*)d_ws;
    u16_t* vimg = kimg + img_elems;
    float* pacc = (float*)((char*)d_ws + img_bytes);
    float* pml  = pacc + rows * D_;
    prep_kernel<<<dim3(B_ * NT * 2), dim3(256), 0, stream>>>(k, v, kimg, vimg);
    attn_main<SPLIT><<<dim3(B_ * 16 * SPLIT), dim3(512), 0, stream>>>(
        q, kimg, vimg, out, pacc, pml);
    combine_kernel<SPLIT><<<dim3((B_ * N_ * D_ / 4) / 256), dim3(256), 0, stream>>>(
        pacc, pml, out);
  } else if (ws_size >= img_bytes) {
    u16_t* kimg = (u16_t*)d_ws;
    u16_t* vimg = kimg + img_elems;
    prep_kernel<<<dim3(B_ * NT * 2), dim3(256), 0, stream>>>(k, v, kimg, vimg);
    attn_main<1><<<dim3(B_ * 16), dim3(512), 0, stream>>>(
        q, kimg, vimg, out, nullptr, nullptr);
  } else {
    attn_fwd_fallback<<<dim3(B_ * 16), dim3(512), 0, stream>>>(q, k, v, out);
  }
}

// Round 8
// 112.154 us; speedup vs baseline: 1.3041x; 1.3041x over previous
//
#include <hip/hip_runtime.h>

#define B_  16
#define N_  2048
#define D_  64
#define QB  128     // q rows per block (main kernel)
#define KB  64      // kv rows per tile
#define NT  (N_/KB) // 32 tiles
#define NW  8       // waves per block (512 threads)
#define TILE_ELEMS (KB * D_)   // 4096 bf16 elements per tile image

typedef __attribute__((ext_vector_type(8))) short short8;
typedef __attribute__((ext_vector_type(4))) float f32x4;
typedef unsigned short u16_t;

static __device__ __forceinline__ unsigned cvt_pk_bf16(float lo, float hi) {
  unsigned r;
  asm("v_cvt_pk_bf16_f32 %0, %1, %2" : "=v"(r) : "v"(lo), "v"(hi));
  return r;
}
static __device__ __forceinline__ float exp2_fast(float x) {
  float r;
  asm("v_exp_f32 %0, %1" : "=v"(r) : "v"(x));
  return r;
}
static __device__ __forceinline__ void gload_lds16(const void* g, void* l) {
  __builtin_amdgcn_global_load_lds(
      (const __attribute__((address_space(1))) unsigned*)g,
      (__attribute__((address_space(3))) unsigned*)l, 16, 0, 0);
}

union U8 { unsigned u[4]; short8 s8; };

// ---------------------------------------------------------------------------
// Pre-pass: K,V (f32) -> bf16 tile images in the exact swizzled (V: transposed)
// layout the main kernel's LDS expects.
// ---------------------------------------------------------------------------
__global__ __launch_bounds__(256) void prep_kernel(
    const float* __restrict__ kg, const float* __restrict__ vg,
    u16_t* __restrict__ kimg, u16_t* __restrict__ vimg) {
  const int bid = blockIdx.x;
  const int isV = bid & 1;
  const int tileid = bid >> 1;
  const float* src = (isV ? vg : kg) + (size_t)tileid * TILE_ELEMS;
  u16_t* dst = (isV ? vimg : kimg) + (size_t)tileid * TILE_ELEMS;
  const int tid = threadIdx.x;

  if (!isV) {
#pragma unroll
    for (int p = 0; p < 2; ++p) {
      int c = tid + p * 256;
      int row = c >> 3, c8 = c & 7;
      const float* sp = src + row * 64 + c8 * 8;
      float4 f0 = *(const float4*)sp;
      float4 f1 = *(const float4*)(sp + 4);
      uint4 u;
      u.x = cvt_pk_bf16(f0.x, f0.y);
      u.y = cvt_pk_bf16(f0.z, f0.w);
      u.z = cvt_pk_bf16(f1.x, f1.y);
      u.w = cvt_pk_bf16(f1.z, f1.w);
      *(uint4*)&dst[(row * 64 + c8 * 8) ^ ((row & 7) << 3)] = u;
    }
  } else {
    __shared__ float Vl[64][68];
    int row = tid >> 2, q4 = (tid & 3) * 16;
    const float* sp = src + row * 64 + q4;
#pragma unroll
    for (int i = 0; i < 4; ++i)
      *(float4*)&Vl[row][q4 + i * 4] = *(const float4*)(sp + i * 4);
    __syncthreads();
#pragma unroll
    for (int p = 0; p < 2; ++p) {
      int c = tid + p * 256;
      int d = c >> 3, kc = c & 7;
      float x[8];
#pragma unroll
      for (int j = 0; j < 8; ++j) x[j] = Vl[kc * 8 + j][d];
      uint4 u;
      u.x = cvt_pk_bf16(x[0], x[1]);
      u.y = cvt_pk_bf16(x[2], x[3]);
      u.z = cvt_pk_bf16(x[4], x[5]);
      u.w = cvt_pk_bf16(x[6], x[7]);
      *(uint4*)&dst[(d * 64 + kc * 8) ^ ((d & 7) << 3)] = u;
    }
  }
}

// ---------------------------------------------------------------------------
// Main flash-attention kernel, templated on KV-split count.
// EXACT R4 configuration (known-good): (512,6), Pl-LDS PV path, 48KB LDS.
// NOTE: do NOT change launch_bounds here — (512,4) miscomputes (R6/R7,
// absmax ~0.36, mechanism unresolved); (512,6)/(512,8)/(512,2) verified good.
// ---------------------------------------------------------------------------
template <int SPLIT>
__global__ __launch_bounds__(512, 6) void attn_main(
    const float* __restrict__ qg, const u16_t* __restrict__ kimg,
    const u16_t* __restrict__ vimg, float* __restrict__ outg,
    float* __restrict__ pacc, float* __restrict__ pml) {
  constexpr int TS = NT / SPLIT;
  __shared__ __align__(16) u16_t Kl[2][TILE_ELEMS];
  __shared__ __align__(16) u16_t Vt[2][TILE_ELEMS];
  __shared__ __align__(16) u16_t Pl[NW][16 * KB];

  const int tid = threadIdx.x;
  const int w = tid >> 6, l = tid & 63;
  const int g = l >> 4, qi = l & 15;

  // bijective XCD chunk swizzle: same-batch blocks stay on one XCD's L2
  constexpr int TOT = B_ * 16 * SPLIT;
  const int bidx = blockIdx.x;
  const int logical = (bidx & 7) * (TOT / 8) + (bidx >> 3);
  const int s  = logical & (SPLIT - 1);
  const int qt = (logical / SPLIT) & 15;
  const int b  = logical / (SPLIT * 16);
  const int q0 = qt * QB + w * 16;

  // ---- Q fragments, prescaled by (1/sqrt(64))*log2(e) for exp2 softmax ----
  short8 qf[2];
  {
    const float sc = 0.18033688011112042f;  // 0.125 * log2(e)
    const float* qp = qg + ((size_t)(b * N_ + q0 + qi)) * D_;
#pragma unroll
    for (int dc = 0; dc < 2; ++dc) {
      float4 f0 = *(const float4*)(qp + dc * 32 + g * 8);
      float4 f1 = *(const float4*)(qp + dc * 32 + g * 8 + 4);
      U8 u;
      u.u[0] = cvt_pk_bf16(f0.x * sc, f0.y * sc);
      u.u[1] = cvt_pk_bf16(f0.z * sc, f0.w * sc);
      u.u[2] = cvt_pk_bf16(f1.x * sc, f1.y * sc);
      u.u[3] = cvt_pk_bf16(f1.z * sc, f1.w * sc);
      qf[dc] = u.s8;
    }
  }

  f32x4 acc[4] = {{0,0,0,0},{0,0,0,0},{0,0,0,0},{0,0,0,0}};
  float m_run = -INFINITY;
  float l_run = 0.f;

  const u16_t* kt = kimg + (size_t)b * NT * TILE_ELEMS;
  const u16_t* vt = vimg + (size_t)b * NT * TILE_ELEMS;

  auto stage = [&](int bb, int tt) {
    const u16_t* kp = kt + (size_t)tt * TILE_ELEMS + w * 512 + l * 8;
    const u16_t* vp = vt + (size_t)tt * TILE_ELEMS + w * 512 + l * 8;
    gload_lds16(kp, &Kl[bb][w * 512]);
    gload_lds16(vp, &Vt[bb][w * 512]);
  };

  const int t0 = s * TS;
  stage(0, t0);
  __syncthreads();

  for (int i = 0; i < TS; ++i) {
    const int cur = i & 1;
    if (i + 1 < TS) stage(cur ^ 1, t0 + i + 1);   // issue-early
    const u16_t* Kc = Kl[cur];
    const u16_t* Vc = Vt[cur];

    // ---- QK^T swapped: lane(g,qi) holds S[q=qi][kv=kvt*16+g*4+r] (log2 dom) ----
    f32x4 st[4];
    __builtin_amdgcn_s_setprio(1);
#pragma unroll
    for (int kvt = 0; kvt < 4; ++kvt) {
      int kvr = kvt * 16 + qi;
      int base = kvr * 64, sw = (kvr & 7) << 3;
      short8 kf0 = *(const short8*)&Kc[(base + g * 8) ^ sw];
      short8 kf1 = *(const short8*)&Kc[(base + 32 + g * 8) ^ sw];
      f32x4 z = {0, 0, 0, 0};
      z = __builtin_amdgcn_mfma_f32_16x16x32_bf16(kf0, qf[0], z, 0, 0, 0);
      z = __builtin_amdgcn_mfma_f32_16x16x32_bf16(kf1, qf[1], z, 0, 0, 0);
      st[kvt] = z;
    }
    __builtin_amdgcn_s_setprio(0);

    // ---- online softmax, exp2 domain, defer-max (THR=8) ----
    float m01 = fmaxf(fmaxf(st[0][0], st[0][1]), fmaxf(st[0][2], st[0][3]));
    float m23 = fmaxf(fmaxf(st[1][0], st[1][1]), fmaxf(st[1][2], st[1][3]));
    float m45 = fmaxf(fmaxf(st[2][0], st[2][1]), fmaxf(st[2][2], st[2][3]));
    float m67 = fmaxf(fmaxf(st[3][0], st[3][1]), fmaxf(st[3][2], st[3][3]));
    float mloc = fmaxf(fmaxf(m01, m23), fmaxf(m45, m67));
    mloc = fmaxf(mloc, __shfl_xor(mloc, 16));
    mloc = fmaxf(mloc, __shfl_xor(mloc, 32));
    if (__any(mloc > m_run + 8.0f)) {
      float mnew = fmaxf(m_run, mloc);
      float alpha = exp2_fast(m_run - mnew);
      m_run = mnew;
      l_run *= alpha;
#pragma unroll
      for (int dt = 0; dt < 4; ++dt)
#pragma unroll
        for (int r = 0; r < 4; ++r) acc[dt][r] *= alpha;
    }
    float ps = 0.f;
#pragma unroll
    for (int kvt = 0; kvt < 4; ++kvt)
#pragma unroll
      for (int r = 0; r < 4; ++r) {
        float p = exp2_fast(st[kvt][r] - m_run);
        st[kvt][r] = p;
        ps += p;
      }
    ps += __shfl_xor(ps, 16);
    ps += __shfl_xor(ps, 32);
    l_run += ps;

    // ---- pack P to bf16 via per-wave swizzled LDS (wave-internal) ----
#pragma unroll
    for (int kvt = 0; kvt < 4; ++kvt) {
      unsigned u0 = cvt_pk_bf16(st[kvt][0], st[kvt][1]);
      unsigned u1 = cvt_pk_bf16(st[kvt][2], st[kvt][3]);
      int kv = kvt * 16 + g * 4;
      int sw = (qi & 7) << 3;
      *(unsigned*)&Pl[w][(qi * 64 + kv) ^ sw]     = u0;
      *(unsigned*)&Pl[w][(qi * 64 + kv + 2) ^ sw] = u1;
    }
    asm volatile("s_waitcnt lgkmcnt(0)" ::: "memory");

    // ---- PV swapped: acc[dt][r] = O_partial[q=qi][d=dt*16+g*4+r] ----
    __builtin_amdgcn_s_setprio(1);
#pragma unroll
    for (int kk = 0; kk < 2; ++kk) {
      short8 pf = *(const short8*)&Pl[w][(qi * 64 + kk * 32 + g * 8) ^ ((qi & 7) << 3)];
#pragma unroll
      for (int dt = 0; dt < 4; ++dt) {
        int d = dt * 16 + qi;
        short8 vf = *(const short8*)&Vc[(d * 64 + kk * 32 + g * 8) ^ ((d & 7) << 3)];
        acc[dt] = __builtin_amdgcn_mfma_f32_16x16x32_bf16(vf, pf, acc[dt], 0, 0, 0);
      }
    }
    __builtin_amdgcn_s_setprio(0);
    __syncthreads();
  }

  const int wq = w * 16 + qi;
  if constexpr (SPLIT == 1) {
    float rl = 1.0f / l_run;
    float* op = outg + ((size_t)(b * N_ + qt * QB + wq)) * D_;
#pragma unroll
    for (int dt = 0; dt < 4; ++dt) {
      float4 o;
      o.x = acc[dt][0] * rl;
      o.y = acc[dt][1] * rl;
      o.z = acc[dt][2] * rl;
      o.w = acc[dt][3] * rl;
      *(float4*)(op + dt * 16 + g * 4) = o;
    }
  } else {
    const size_t rowid = (size_t)logical * QB + wq;
    float* ap = pacc + rowid * D_;
#pragma unroll
    for (int dt = 0; dt < 4; ++dt) {
      float4 o;
      o.x = acc[dt][0]; o.y = acc[dt][1]; o.z = acc[dt][2]; o.w = acc[dt][3];
      *(float4*)(ap + dt * 16 + g * 4) = o;
    }
    if (g == 0) *(float2*)&pml[rowid * 2] = make_float2(m_run, l_run);
  }
}

// ---------------------------------------------------------------------------
// Combine: merge SPLIT partials per q-row (log2-domain flash merge).
// ---------------------------------------------------------------------------
template <int SPLIT>
__global__ __launch_bounds__(256) void combine_kernel(
    const float* __restrict__ pacc, const float* __restrict__ pml,
    float* __restrict__ outg) {
  const int fid = blockIdx.x * 256 + threadIdx.x;
  const int q = fid >> 4;
  const int c = fid & 15;
  const int b = q >> 11, rem = q & 2047;
  const int qt = rem >> 7, wq = rem & 127;
  const size_t base = ((size_t)(b * 16 + qt) * SPLIT) * QB + wq;

  float m[SPLIT], lv[SPLIT];
#pragma unroll
  for (int s2 = 0; s2 < SPLIT; ++s2) {
    float2 ml = *(const float2*)&pml[(base + (size_t)s2 * QB) * 2];
    m[s2] = ml.x; lv[s2] = ml.y;
  }
  float ms = m[0];
#pragma unroll
  for (int s2 = 1; s2 < SPLIT; ++s2) ms = fmaxf(ms, m[s2]);
  float L = 0.f, wgt[SPLIT];
#pragma unroll
  for (int s2 = 0; s2 < SPLIT; ++s2) {
    wgt[s2] = exp2_fast(m[s2] - ms);
    L += wgt[s2] * lv[s2];
  }
  float rl = 1.0f / L;

  float4 o = {0.f, 0.f, 0.f, 0.f};
#pragma unroll
  for (int s2 = 0; s2 < SPLIT; ++s2) {
    float4 a = *(const float4*)&pacc[(base + (size_t)s2 * QB) * D_ + c * 4];
    o.x += wgt[s2] * a.x;
    o.y += wgt[s2] * a.y;
    o.z += wgt[s2] * a.z;
    o.w += wgt[s2] * a.w;
  }
  o.x *= rl; o.y *= rl; o.z *= rl; o.w *= rl;
  *(float4*)&outg[(size_t)fid * 4] = o;
}

// ---------------------------------------------------------------------------
// Fallback (known-good R2 kernel) if workspace is too small.
// ---------------------------------------------------------------------------
__global__ __launch_bounds__(512, 2) void attn_fwd_fallback(
    const float* __restrict__ qg, const float* __restrict__ kg,
    const float* __restrict__ vg, float* __restrict__ outg) {
  __shared__ __align__(16) u16_t Kl[KB * D_];
  __shared__ __align__(16) u16_t Vt[D_ * KB];
  __shared__ __align__(16) u16_t Pl[NW][16 * KB];

  const int tid = threadIdx.x;
  const int w = tid >> 6, l = tid & 63;
  const int g = l >> 4, qi = l & 15;
  const int bidx = blockIdx.x;
  const int b = bidx >> 4, qt = bidx & 15;
  const int q0 = qt * QB + w * 16;

  short8 qf[2];
  {
    const float* qp = qg + ((size_t)(b * N_ + q0 + qi)) * D_;
    const float sc = 0.125f;
#pragma unroll
    for (int dc = 0; dc < 2; ++dc) {
      float4 f0 = *(const float4*)(qp + dc * 32 + g * 8);
      float4 f1 = *(const float4*)(qp + dc * 32 + g * 8 + 4);
      U8 u;
      u.u[0] = cvt_pk_bf16(f0.x * sc, f0.y * sc);
      u.u[1] = cvt_pk_bf16(f0.z * sc, f0.w * sc);
      u.u[2] = cvt_pk_bf16(f1.x * sc, f1.y * sc);
      u.u[3] = cvt_pk_bf16(f1.z * sc, f1.w * sc);
      qf[dc] = u.s8;
    }
  }

  f32x4 acc[4] = {{0,0,0,0},{0,0,0,0},{0,0,0,0},{0,0,0,0}};
  float m_run = -INFINITY, l_run = 0.f;
  const float* kbase = kg + (size_t)b * N_ * D_;
  const float* vbase = vg + (size_t)b * N_ * D_;

  for (int kv0 = 0; kv0 < N_; kv0 += KB) {
#pragma unroll
    for (int p = 0; p < 2; ++p) {
      int idx = tid + p * 512;
      int row = idx >> 4, c4 = idx & 15;
      float4 f = *(const float4*)(kbase + (size_t)(kv0 + row) * D_ + c4 * 4);
      unsigned u0 = cvt_pk_bf16(f.x, f.y);
      unsigned u1 = cvt_pk_bf16(f.z, f.w);
      int o = (row * 64 + c4 * 4) ^ ((row & 7) << 3);
      *(uint2*)&Kl[o] = make_uint2(u0, u1);
    }
    {
      int rp = tid >> 4, c4 = tid & 15;
      int row2 = rp * 2;
      const float* vp = vbase + (size_t)(kv0 + row2) * D_ + c4 * 4;
      float4 a0 = *(const float4*)vp;
      float4 a1 = *(const float4*)(vp + D_);
      float lo[4] = {a0.x, a0.y, a0.z, a0.w};
      float hi[4] = {a1.x, a1.y, a1.z, a1.w};
#pragma unroll
      for (int i = 0; i < 4; ++i) {
        int d = c4 * 4 + i;
        unsigned u = cvt_pk_bf16(lo[i], hi[i]);
        int o = (d * 64 + row2) ^ ((d & 7) << 3);
        *(unsigned*)&Vt[o] = u;
      }
    }
    __syncthreads();

    f32x4 st[4];
#pragma unroll
    for (int kvt = 0; kvt < 4; ++kvt) {
      int kvr = kvt * 16 + qi;
      int base = kvr * 64, sw = (kvr & 7) << 3;
      short8 kf0 = *(const short8*)&Kl[(base + g * 8) ^ sw];
      short8 kf1 = *(const short8*)&Kl[(base + 32 + g * 8) ^ sw];
      f32x4 z = {0, 0, 0, 0};
      z = __builtin_amdgcn_mfma_f32_16x16x32_bf16(kf0, qf[0], z, 0, 0, 0);
      z = __builtin_amdgcn_mfma_f32_16x16x32_bf16(kf1, qf[1], z, 0, 0, 0);
      st[kvt] = z;
    }

    float mloc = -INFINITY;
#pragma unroll
    for (int kvt = 0; kvt < 4; ++kvt)
#pragma unroll
      for (int r = 0; r < 4; ++r) mloc = fmaxf(mloc, st[kvt][r]);
    mloc = fmaxf(mloc, __shfl_xor(mloc, 16));
    mloc = fmaxf(mloc, __shfl_xor(mloc, 32));
    float mnew = fmaxf(m_run, mloc);
    float alpha = __expf(m_run - mnew);
    m_run = mnew;

    float ps = 0.f;
#pragma unroll
    for (int kvt = 0; kvt < 4; ++kvt)
#pragma unroll
      for (int r = 0; r < 4; ++r) {
        float p = __expf(st[kvt][r] - mnew);
        st[kvt][r] = p;
        ps += p;
      }
    ps += __shfl_xor(ps, 16);
    ps += __shfl_xor(ps, 32);
    l_run = l_run * alpha + ps;

#pragma unroll
    for (int dt = 0; dt < 4; ++dt)
#pragma unroll
      for (int r = 0; r < 4; ++r) acc[dt][r] *= alpha;

#pragma unroll
    for (int kvt = 0; kvt < 4; ++kvt) {
      unsigned u0 = cvt_pk_bf16(st[kvt][0], st[kvt][1]);
      unsigned u1 = cvt_pk_bf16(st[kvt][2], st[kvt][3]);
      int kv = kvt * 16 + g * 4;
      int sw = (qi & 7) << 3;
      *(unsigned*)&Pl[w][(qi * 64 + kv) ^ sw]     = u0;
      *(unsigned*)&Pl[w][(qi * 64 + kv + 2) ^ sw] = u1;
    }
    asm volatile("s_waitcnt lgkmcnt(0)" ::: "memory");

#pragma unroll
    for (int kk = 0; kk < 2; ++kk) {
      short8 pf = *(const short8*)&Pl[w][(qi * 64 + kk * 32 + g * 8) ^ ((qi & 7) << 3)];
#pragma unroll
      for (int dt = 0; dt < 4; ++dt) {
        int d = dt * 16 + qi;
        short8 vf = *(const short8*)&Vt[(d * 64 + kk * 32 + g * 8) ^ ((d & 7) << 3)];
        acc[dt] = __builtin_amdgcn_mfma_f32_16x16x32_bf16(vf, pf, acc[dt], 0, 0, 0);
      }
    }
    __syncthreads();
  }

  float rl = 1.0f / l_run;
  float* op = outg + ((size_t)(b * N_ + q0 + qi)) * D_;
#pragma unroll
  for (int dt = 0; dt < 4; ++dt) {
    float4 o;
    o.x = acc[dt][0] * rl;
    o.y = acc[dt][1] * rl;
    o.z = acc[dt][2] * rl;
    o.w = acc[dt][3] * rl;
    *(float4*)(op + dt * 16 + g * 4) = o;
  }
}

extern "C" void kernel_launch(void* const* d_in, const int* in_sizes, int n_in,
                              void* d_out, int out_size, void* d_ws, size_t ws_size,
                              hipStream_t stream) {
  const float* q = (const float*)d_in[0];
  const float* k = (const float*)d_in[1];
  const float* v = (const float*)d_in[2];
  float* out = (float*)d_out;

  constexpr int SPLIT = 4;
  const size_t img_elems = (size_t)B_ * N_ * D_;            // 2M bf16 per image
  const size_t img_bytes = 2 * img_elems * sizeof(u16_t);   // 8 MB (K+V)
  const size_t rows = (size_t)B_ * N_ * SPLIT;              // partial rows
  const size_t acc_bytes = rows * D_ * sizeof(float);       // 33.5 MB
  const size_t ml_bytes = rows * 2 * sizeof(float);         // 1 MB
  const size_t need_split = img_bytes + acc_bytes + ml_bytes;

  if (ws_size >= need_split) {
    u16_t* kimg = (u16_t*)d_ws;
    u16_t* vimg = kimg + img_elems;
    float* pacc = (float*)((char*)d_ws + img_bytes);
    float* pml  = pacc + rows * D_;
    prep_kernel<<<dim3(B_ * NT * 2), dim3(256), 0, stream>>>(k, v, kimg, vimg);
    attn_main<SPLIT><<<dim3(B_ * 16 * SPLIT), dim3(512), 0, stream>>>(
        q, kimg, vimg, out, pacc, pml);
    combine_kernel<SPLIT><<<dim3((B_ * N_ * D_ / 4) / 256), dim3(256), 0, stream>>>(
        pacc, pml, out);
  } else if (ws_size >= img_bytes) {
    u16_t* kimg = (u16_t*)d_ws;
    u16_t* vimg = kimg + img_elems;
    prep_kernel<<<dim3(B_ * NT * 2), dim3(256), 0, stream>>>(k, v, kimg, vimg);
    attn_main<1><<<dim3(B_ * 16), dim3(512), 0, stream>>>(
        q, kimg, vimg, out, nullptr, nullptr);
  } else {
    attn_fwd_fallback<<<dim3(B_ * 16), dim3(512), 0, stream>>>(q, k, v, out);
  }
}

// Round 10
// 109.790 us; speedup vs baseline: 1.3322x; 1.0215x over previous
//
#include <hip/hip_runtime.h>

#define B_  16
#define N_  2048
#define D_  64
#define QB  128     // q rows per block (main kernel)
#define KB  64      // kv rows per tile
#define NT  (N_/KB) // 32 tiles
#define NW  8       // waves per block (512 threads)
#define TILE_ELEMS (KB * D_)   // 4096 bf16 elements per tile image

typedef __attribute__((ext_vector_type(8))) short short8;
typedef __attribute__((ext_vector_type(4))) float f32x4;
typedef unsigned short u16_t;

static __device__ __forceinline__ unsigned cvt_pk_bf16(float lo, float hi) {
  unsigned r;
  asm("v_cvt_pk_bf16_f32 %0, %1, %2" : "=v"(r) : "v"(lo), "v"(hi));
  return r;
}
static __device__ __forceinline__ float exp2_fast(float x) {
  float r;
  asm("v_exp_f32 %0, %1" : "=v"(r) : "v"(x));
  return r;
}
static __device__ __forceinline__ void gload_lds16(const void* g, void* l) {
  __builtin_amdgcn_global_load_lds(
      (const __attribute__((address_space(1))) unsigned*)g,
      (__attribute__((address_space(3))) unsigned*)l, 16, 0, 0);
}

union U8 { unsigned u[4]; short8 s8; };

// ---------------------------------------------------------------------------
// Pre-pass: K,V (f32) -> bf16 tile images in the exact swizzled (V: transposed)
// layout the main kernel's LDS expects.
// ---------------------------------------------------------------------------
__global__ __launch_bounds__(256) void prep_kernel(
    const float* __restrict__ kg, const float* __restrict__ vg,
    u16_t* __restrict__ kimg, u16_t* __restrict__ vimg) {
  const int bid = blockIdx.x;
  const int isV = bid & 1;
  const int tileid = bid >> 1;
  const float* src = (isV ? vg : kg) + (size_t)tileid * TILE_ELEMS;
  u16_t* dst = (isV ? vimg : kimg) + (size_t)tileid * TILE_ELEMS;
  const int tid = threadIdx.x;

  if (!isV) {
#pragma unroll
    for (int p = 0; p < 2; ++p) {
      int c = tid + p * 256;
      int row = c >> 3, c8 = c & 7;
      const float* sp = src + row * 64 + c8 * 8;
      float4 f0 = *(const float4*)sp;
      float4 f1 = *(const float4*)(sp + 4);
      uint4 u;
      u.x = cvt_pk_bf16(f0.x, f0.y);
      u.y = cvt_pk_bf16(f0.z, f0.w);
      u.z = cvt_pk_bf16(f1.x, f1.y);
      u.w = cvt_pk_bf16(f1.z, f1.w);
      *(uint4*)&dst[(row * 64 + c8 * 8) ^ ((row & 7) << 3)] = u;
    }
  } else {
    __shared__ float Vl[64][68];
    int row = tid >> 2, q4 = (tid & 3) * 16;
    const float* sp = src + row * 64 + q4;
#pragma unroll
    for (int i = 0; i < 4; ++i)
      *(float4*)&Vl[row][q4 + i * 4] = *(const float4*)(sp + i * 4);
    __syncthreads();
#pragma unroll
    for (int p = 0; p < 2; ++p) {
      int c = tid + p * 256;
      int d = c >> 3, kc = c & 7;
      float x[8];
#pragma unroll
      for (int j = 0; j < 8; ++j) x[j] = Vl[kc * 8 + j][d];
      uint4 u;
      u.x = cvt_pk_bf16(x[0], x[1]);
      u.y = cvt_pk_bf16(x[2], x[3]);
      u.z = cvt_pk_bf16(x[4], x[5]);
      u.w = cvt_pk_bf16(x[6], x[7]);
      *(uint4*)&dst[(d * 64 + kc * 8) ^ ((d & 7) << 3)] = u;
    }
  }
}

// ---------------------------------------------------------------------------
// Main flash-attention kernel, templated on KV-split count.
// Config: (512,6) bounds [FROZEN — (512,4) miscomputes, R6/R7], Pl-LDS PV,
// 48KB LDS. Single change vs R8: SPLIT 4 -> 2 (512 blocks = exactly 2/CU
// uniform, no 1-block/CU tail round; partial traffic halved).
// ---------------------------------------------------------------------------
template <int SPLIT>
__global__ __launch_bounds__(512, 6) void attn_main(
    const float* __restrict__ qg, const u16_t* __restrict__ kimg,
    const u16_t* __restrict__ vimg, float* __restrict__ outg,
    float* __restrict__ pacc, float* __restrict__ pml) {
  constexpr int TS = NT / SPLIT;
  __shared__ __align__(16) u16_t Kl[2][TILE_ELEMS];
  __shared__ __align__(16) u16_t Vt[2][TILE_ELEMS];
  __shared__ __align__(16) u16_t Pl[NW][16 * KB];

  const int tid = threadIdx.x;
  const int w = tid >> 6, l = tid & 63;
  const int g = l >> 4, qi = l & 15;

  // bijective XCD chunk swizzle: same-batch blocks stay on one XCD's L2
  constexpr int TOT = B_ * 16 * SPLIT;
  const int bidx = blockIdx.x;
  const int logical = (bidx & 7) * (TOT / 8) + (bidx >> 3);
  const int s  = logical & (SPLIT - 1);
  const int qt = (logical / SPLIT) & 15;
  const int b  = logical / (SPLIT * 16);
  const int q0 = qt * QB + w * 16;

  // ---- Q fragments, prescaled by (1/sqrt(64))*log2(e) for exp2 softmax ----
  short8 qf[2];
  {
    const float sc = 0.18033688011112042f;  // 0.125 * log2(e)
    const float* qp = qg + ((size_t)(b * N_ + q0 + qi)) * D_;
#pragma unroll
    for (int dc = 0; dc < 2; ++dc) {
      float4 f0 = *(const float4*)(qp + dc * 32 + g * 8);
      float4 f1 = *(const float4*)(qp + dc * 32 + g * 8 + 4);
      U8 u;
      u.u[0] = cvt_pk_bf16(f0.x * sc, f0.y * sc);
      u.u[1] = cvt_pk_bf16(f0.z * sc, f0.w * sc);
      u.u[2] = cvt_pk_bf16(f1.x * sc, f1.y * sc);
      u.u[3] = cvt_pk_bf16(f1.z * sc, f1.w * sc);
      qf[dc] = u.s8;
    }
  }

  f32x4 acc[4] = {{0,0,0,0},{0,0,0,0},{0,0,0,0},{0,0,0,0}};
  float m_run = -INFINITY;
  float l_run = 0.f;

  const u16_t* kt = kimg + (size_t)b * NT * TILE_ELEMS;
  const u16_t* vt = vimg + (size_t)b * NT * TILE_ELEMS;

  auto stage = [&](int bb, int tt) {
    const u16_t* kp = kt + (size_t)tt * TILE_ELEMS + w * 512 + l * 8;
    const u16_t* vp = vt + (size_t)tt * TILE_ELEMS + w * 512 + l * 8;
    gload_lds16(kp, &Kl[bb][w * 512]);
    gload_lds16(vp, &Vt[bb][w * 512]);
  };

  const int t0 = s * TS;
  stage(0, t0);
  __syncthreads();

  for (int i = 0; i < TS; ++i) {
    const int cur = i & 1;
    if (i + 1 < TS) stage(cur ^ 1, t0 + i + 1);   // issue-early
    const u16_t* Kc = Kl[cur];
    const u16_t* Vc = Vt[cur];

    // ---- QK^T swapped: lane(g,qi) holds S[q=qi][kv=kvt*16+g*4+r] (log2 dom) ----
    f32x4 st[4];
    __builtin_amdgcn_s_setprio(1);
#pragma unroll
    for (int kvt = 0; kvt < 4; ++kvt) {
      int kvr = kvt * 16 + qi;
      int base = kvr * 64, sw = (kvr & 7) << 3;
      short8 kf0 = *(const short8*)&Kc[(base + g * 8) ^ sw];
      short8 kf1 = *(const short8*)&Kc[(base + 32 + g * 8) ^ sw];
      f32x4 z = {0, 0, 0, 0};
      z = __builtin_amdgcn_mfma_f32_16x16x32_bf16(kf0, qf[0], z, 0, 0, 0);
      z = __builtin_amdgcn_mfma_f32_16x16x32_bf16(kf1, qf[1], z, 0, 0, 0);
      st[kvt] = z;
    }
    __builtin_amdgcn_s_setprio(0);

    // ---- online softmax, exp2 domain, defer-max (THR=8) ----
    float m01 = fmaxf(fmaxf(st[0][0], st[0][1]), fmaxf(st[0][2], st[0][3]));
    float m23 = fmaxf(fmaxf(st[1][0], st[1][1]), fmaxf(st[1][2], st[1][3]));
    float m45 = fmaxf(fmaxf(st[2][0], st[2][1]), fmaxf(st[2][2], st[2][3]));
    float m67 = fmaxf(fmaxf(st[3][0], st[3][1]), fmaxf(st[3][2], st[3][3]));
    float mloc = fmaxf(fmaxf(m01, m23), fmaxf(m45, m67));
    mloc = fmaxf(mloc, __shfl_xor(mloc, 16));
    mloc = fmaxf(mloc, __shfl_xor(mloc, 32));
    if (__any(mloc > m_run + 8.0f)) {
      float mnew = fmaxf(m_run, mloc);
      float alpha = exp2_fast(m_run - mnew);
      m_run = mnew;
      l_run *= alpha;
#pragma unroll
      for (int dt = 0; dt < 4; ++dt)
#pragma unroll
        for (int r = 0; r < 4; ++r) acc[dt][r] *= alpha;
    }
    float ps = 0.f;
#pragma unroll
    for (int kvt = 0; kvt < 4; ++kvt)
#pragma unroll
      for (int r = 0; r < 4; ++r) {
        float p = exp2_fast(st[kvt][r] - m_run);
        st[kvt][r] = p;
        ps += p;
      }
    ps += __shfl_xor(ps, 16);
    ps += __shfl_xor(ps, 32);
    l_run += ps;

    // ---- pack P to bf16 via per-wave swizzled LDS (wave-internal) ----
#pragma unroll
    for (int kvt = 0; kvt < 4; ++kvt) {
      unsigned u0 = cvt_pk_bf16(st[kvt][0], st[kvt][1]);
      unsigned u1 = cvt_pk_bf16(st[kvt][2], st[kvt][3]);
      int kv = kvt * 16 + g * 4;
      int sw = (qi & 7) << 3;
      *(unsigned*)&Pl[w][(qi * 64 + kv) ^ sw]     = u0;
      *(unsigned*)&Pl[w][(qi * 64 + kv + 2) ^ sw] = u1;
    }
    asm volatile("s_waitcnt lgkmcnt(0)" ::: "memory");

    // ---- PV swapped: acc[dt][r] = O_partial[q=qi][d=dt*16+g*4+r] ----
    __builtin_amdgcn_s_setprio(1);
#pragma unroll
    for (int kk = 0; kk < 2; ++kk) {
      short8 pf = *(const short8*)&Pl[w][(qi * 64 + kk * 32 + g * 8) ^ ((qi & 7) << 3)];
#pragma unroll
      for (int dt = 0; dt < 4; ++dt) {
        int d = dt * 16 + qi;
        short8 vf = *(const short8*)&Vc[(d * 64 + kk * 32 + g * 8) ^ ((d & 7) << 3)];
        acc[dt] = __builtin_amdgcn_mfma_f32_16x16x32_bf16(vf, pf, acc[dt], 0, 0, 0);
      }
    }
    __builtin_amdgcn_s_setprio(0);
    __syncthreads();
  }

  const int wq = w * 16 + qi;
  if constexpr (SPLIT == 1) {
    float rl = 1.0f / l_run;
    float* op = outg + ((size_t)(b * N_ + qt * QB + wq)) * D_;
#pragma unroll
    for (int dt = 0; dt < 4; ++dt) {
      float4 o;
      o.x = acc[dt][0] * rl;
      o.y = acc[dt][1] * rl;
      o.z = acc[dt][2] * rl;
      o.w = acc[dt][3] * rl;
      *(float4*)(op + dt * 16 + g * 4) = o;
    }
  } else {
    const size_t rowid = (size_t)logical * QB + wq;
    float* ap = pacc + rowid * D_;
#pragma unroll
    for (int dt = 0; dt < 4; ++dt) {
      float4 o;
      o.x = acc[dt][0]; o.y = acc[dt][1]; o.z = acc[dt][2]; o.w = acc[dt][3];
      *(float4*)(ap + dt * 16 + g * 4) = o;
    }
    if (g == 0) *(float2*)&pml[rowid * 2] = make_float2(m_run, l_run);
  }
}

// ---------------------------------------------------------------------------
// Combine: merge SPLIT partials per q-row (log2-domain flash merge).
// ---------------------------------------------------------------------------
template <int SPLIT>
__global__ __launch_bounds__(256) void combine_kernel(
    const float* __restrict__ pacc, const float* __restrict__ pml,
    float* __restrict__ outg) {
  const int fid = blockIdx.x * 256 + threadIdx.x;
  const int q = fid >> 4;
  const int c = fid & 15;
  const int b = q >> 11, rem = q & 2047;
  const int qt = rem >> 7, wq = rem & 127;
  const size_t base = ((size_t)(b * 16 + qt) * SPLIT) * QB + wq;

  float m[SPLIT], lv[SPLIT];
#pragma unroll
  for (int s2 = 0; s2 < SPLIT; ++s2) {
    float2 ml = *(const float2*)&pml[(base + (size_t)s2 * QB) * 2];
    m[s2] = ml.x; lv[s2] = ml.y;
  }
  float ms = m[0];
#pragma unroll
  for (int s2 = 1; s2 < SPLIT; ++s2) ms = fmaxf(ms, m[s2]);
  float L = 0.f, wgt[SPLIT];
#pragma unroll
  for (int s2 = 0; s2 < SPLIT; ++s2) {
    wgt[s2] = exp2_fast(m[s2] - ms);
    L += wgt[s2] * lv[s2];
  }
  float rl = 1.0f / L;

  float4 o = {0.f, 0.f, 0.f, 0.f};
#pragma unroll
  for (int s2 = 0; s2 < SPLIT; ++s2) {
    float4 a = *(const float4*)&pacc[(base + (size_t)s2 * QB) * D_ + c * 4];
    o.x += wgt[s2] * a.x;
    o.y += wgt[s2] * a.y;
    o.z += wgt[s2] * a.z;
    o.w += wgt[s2] * a.w;
  }
  o.x *= rl; o.y *= rl; o.z *= rl; o.w *= rl;
  *(float4*)&outg[(size_t)fid * 4] = o;
}

// ---------------------------------------------------------------------------
// Fallback (known-good R2 kernel) if workspace is too small.
// ---------------------------------------------------------------------------
__global__ __launch_bounds__(512, 2) void attn_fwd_fallback(
    const float* __restrict__ qg, const float* __restrict__ kg,
    const float* __restrict__ vg, float* __restrict__ outg) {
  __shared__ __align__(16) u16_t Kl[KB * D_];
  __shared__ __align__(16) u16_t Vt[D_ * KB];
  __shared__ __align__(16) u16_t Pl[NW][16 * KB];

  const int tid = threadIdx.x;
  const int w = tid >> 6, l = tid & 63;
  const int g = l >> 4, qi = l & 15;
  const int bidx = blockIdx.x;
  const int b = bidx >> 4, qt = bidx & 15;
  const int q0 = qt * QB + w * 16;

  short8 qf[2];
  {
    const float* qp = qg + ((size_t)(b * N_ + q0 + qi)) * D_;
    const float sc = 0.125f;
#pragma unroll
    for (int dc = 0; dc < 2; ++dc) {
      float4 f0 = *(const float4*)(qp + dc * 32 + g * 8);
      float4 f1 = *(const float4*)(qp + dc * 32 + g * 8 + 4);
      U8 u;
      u.u[0] = cvt_pk_bf16(f0.x * sc, f0.y * sc);
      u.u[1] = cvt_pk_bf16(f0.z * sc, f0.w * sc);
      u.u[2] = cvt_pk_bf16(f1.x * sc, f1.y * sc);
      u.u[3] = cvt_pk_bf16(f1.z * sc, f1.w * sc);
      qf[dc] = u.s8;
    }
  }

  f32x4 acc[4] = {{0,0,0,0},{0,0,0,0},{0,0,0,0},{0,0,0,0}};
  float m_run = -INFINITY, l_run = 0.f;
  const float* kbase = kg + (size_t)b * N_ * D_;
  const float* vbase = vg + (size_t)b * N_ * D_;

  for (int kv0 = 0; kv0 < N_; kv0 += KB) {
#pragma unroll
    for (int p = 0; p < 2; ++p) {
      int idx = tid + p * 512;
      int row = idx >> 4, c4 = idx & 15;
      float4 f = *(const float4*)(kbase + (size_t)(kv0 + row) * D_ + c4 * 4);
      unsigned u0 = cvt_pk_bf16(f.x, f.y);
      unsigned u1 = cvt_pk_bf16(f.z, f.w);
      int o = (row * 64 + c4 * 4) ^ ((row & 7) << 3);
      *(uint2*)&Kl[o] = make_uint2(u0, u1);
    }
    {
      int rp = tid >> 4, c4 = tid & 15;
      int row2 = rp * 2;
      const float* vp = vbase + (size_t)(kv0 + row2) * D_ + c4 * 4;
      float4 a0 = *(const float4*)vp;
      float4 a1 = *(const float4*)(vp + D_);
      float lo[4] = {a0.x, a0.y, a0.z, a0.w};
      float hi[4] = {a1.x, a1.y, a1.z, a1.w};
#pragma unroll
      for (int i = 0; i < 4; ++i) {
        int d = c4 * 4 + i;
        unsigned u = cvt_pk_bf16(lo[i], hi[i]);
        int o = (d * 64 + row2) ^ ((d & 7) << 3);
        *(unsigned*)&Vt[o] = u;
      }
    }
    __syncthreads();

    f32x4 st[4];
#pragma unroll
    for (int kvt = 0; kvt < 4; ++kvt) {
      int kvr = kvt * 16 + qi;
      int base = kvr * 64, sw = (kvr & 7) << 3;
      short8 kf0 = *(const short8*)&Kl[(base + g * 8) ^ sw];
      short8 kf1 = *(const short8*)&Kl[(base + 32 + g * 8) ^ sw];
      f32x4 z = {0, 0, 0, 0};
      z = __builtin_amdgcn_mfma_f32_16x16x32_bf16(kf0, qf[0], z, 0, 0, 0);
      z = __builtin_amdgcn_mfma_f32_16x16x32_bf16(kf1, qf[1], z, 0, 0, 0);
      st[kvt] = z;
    }

    float mloc = -INFINITY;
#pragma unroll
    for (int kvt = 0; kvt < 4; ++kvt)
#pragma unroll
      for (int r = 0; r < 4; ++r) mloc = fmaxf(mloc, st[kvt][r]);
    mloc = fmaxf(mloc, __shfl_xor(mloc, 16));
    mloc = fmaxf(mloc, __shfl_xor(mloc, 32));
    float mnew = fmaxf(m_run, mloc);
    float alpha = __expf(m_run - mnew);
    m_run = mnew;

    float ps = 0.f;
#pragma unroll
    for (int kvt = 0; kvt < 4; ++kvt)
#pragma unroll
      for (int r = 0; r < 4; ++r) {
        float p = __expf(st[kvt][r] - mnew);
        st[kvt][r] = p;
        ps += p;
      }
    ps += __shfl_xor(ps, 16);
    ps += __shfl_xor(ps, 32);
    l_run = l_run * alpha + ps;

#pragma unroll
    for (int dt = 0; dt < 4; ++dt)
#pragma unroll
      for (int r = 0; r < 4; ++r) acc[dt][r] *= alpha;

#pragma unroll
    for (int kvt = 0; kvt < 4; ++kvt) {
      unsigned u0 = cvt_pk_bf16(st[kvt][0], st[kvt][1]);
      unsigned u1 = cvt_pk_bf16(st[kvt][2], st[kvt][3]);
      int kv = kvt * 16 + g * 4;
      int sw = (qi & 7) << 3;
      *(unsigned*)&Pl[w][(qi * 64 + kv) ^ sw]     = u0;
      *(unsigned*)&Pl[w][(qi * 64 + kv + 2) ^ sw] = u1;
    }
    asm volatile("s_waitcnt lgkmcnt(0)" ::: "memory");

#pragma unroll
    for (int kk = 0; kk < 2; ++kk) {
      short8 pf = *(const short8*)&Pl[w][(qi * 64 + kk * 32 + g * 8) ^ ((qi & 7) << 3)];
#pragma unroll
      for (int dt = 0; dt < 4; ++dt) {
        int d = dt * 16 + qi;
        short8 vf = *(const short8*)&Vt[(d * 64 + kk * 32 + g * 8) ^ ((d & 7) << 3)];
        acc[dt] = __builtin_amdgcn_mfma_f32_16x16x32_bf16(vf, pf, acc[dt], 0, 0, 0);
      }
    }
    __syncthreads();
  }

  float rl = 1.0f / l_run;
  float* op = outg + ((size_t)(b * N_ + q0 + qi)) * D_;
#pragma unroll
  for (int dt = 0; dt < 4; ++dt) {
    float4 o;
    o.x = acc[dt][0] * rl;
    o.y = acc[dt][1] * rl;
    o.z = acc[dt][2] * rl;
    o.w = acc[dt][3] * rl;
    *(float4*)(op + dt * 16 + g * 4) = o;
  }
}

extern "C" void kernel_launch(void* const* d_in, const int* in_sizes, int n_in,
                              void* d_out, int out_size, void* d_ws, size_t ws_size,
                              hipStream_t stream) {
  const float* q = (const float*)d_in[0];
  const float* k = (const float*)d_in[1];
  const float* v = (const float*)d_in[2];
  float* out = (float*)d_out;

  constexpr int SPLIT = 2;
  const size_t img_elems = (size_t)B_ * N_ * D_;            // 2M bf16 per image
  const size_t img_bytes = 2 * img_elems * sizeof(u16_t);   // 8 MB (K+V)
  const size_t rows = (size_t)B_ * N_ * SPLIT;              // partial rows
  const size_t acc_bytes = rows * D_ * sizeof(float);       // 16.8 MB
  const size_t ml_bytes = rows * 2 * sizeof(float);         // 0.5 MB
  const size_t need_split = img_bytes + acc_bytes + ml_bytes;

  if (ws_size >= need_split) {
    u16_t* kimg = (u16_t*)d_ws;
    u16_t* vimg = kimg + img_elems;
    float* pacc = (float*)((char*)d_ws + img_bytes);
    float* pml  = pacc + rows * D_;
    prep_kernel<<<dim3(B_ * NT * 2), dim3(256), 0, stream>>>(k, v, kimg, vimg);
    attn_main<SPLIT><<<dim3(B_ * 16 * SPLIT), dim3(512), 0, stream>>>(
        q, kimg, vimg, out, pacc, pml);
    combine_kernel<SPLIT><<<dim3((B_ * N_ * D_ / 4) / 256), dim3(256), 0, stream>>>(
        pacc, pml, out);
  } else if (ws_size >= img_bytes) {
    u16_t* kimg = (u16_t*)d_ws;
    u16_t* vimg = kimg + img_elems;
    prep_kernel<<<dim3(B_ * NT * 2), dim3(256), 0, stream>>>(k, v, kimg, vimg);
    attn_main<1><<<dim3(B_ * 16), dim3(512), 0, stream>>>(
        q, kimg, vimg, out, nullptr, nullptr);
  } else {
    attn_fwd_fallback<<<dim3(B_ * 16), dim3(512), 0, stream>>>(q, k, v, out);
  }
}

// Round 12
// 108.825 us; speedup vs baseline: 1.3440x; 1.0089x over previous
//
#include <hip/hip_runtime.h>

#define B_  16
#define N_  2048
#define D_  64
#define QB  128     // q rows per block (main kernel)
#define KB  64      // kv rows per tile
#define NT  (N_/KB) // 32 tiles
#define NW  8       // waves per block (512 threads)
#define TILE_ELEMS (KB * D_)   // 4096 bf16 elements per tile image

typedef __attribute__((ext_vector_type(8))) short short8;
typedef __attribute__((ext_vector_type(4))) float f32x4;
typedef unsigned short u16_t;

static __device__ __forceinline__ unsigned cvt_pk_bf16(float lo, float hi) {
  unsigned r;
  asm("v_cvt_pk_bf16_f32 %0, %1, %2" : "=v"(r) : "v"(lo), "v"(hi));
  return r;
}
static __device__ __forceinline__ float exp2_fast(float x) {
  float r;
  asm("v_exp_f32 %0, %1" : "=v"(r) : "v"(x));
  return r;
}
static __device__ __forceinline__ void gload_lds16(const void* g, void* l) {
  __builtin_amdgcn_global_load_lds(
      (const __attribute__((address_space(1))) unsigned*)g,
      (__attribute__((address_space(3))) unsigned*)l, 16, 0, 0);
}

union U8 { unsigned u[4]; short8 s8; };

// ---------------------------------------------------------------------------
// Pre-pass: K,V (f32) -> bf16 tile images in the exact swizzled (V: transposed)
// layout the main kernel's LDS expects.
// ---------------------------------------------------------------------------
__global__ __launch_bounds__(256) void prep_kernel(
    const float* __restrict__ kg, const float* __restrict__ vg,
    u16_t* __restrict__ kimg, u16_t* __restrict__ vimg) {
  const int bid = blockIdx.x;
  const int isV = bid & 1;
  const int tileid = bid >> 1;
  const float* src = (isV ? vg : kg) + (size_t)tileid * TILE_ELEMS;
  u16_t* dst = (isV ? vimg : kimg) + (size_t)tileid * TILE_ELEMS;
  const int tid = threadIdx.x;

  if (!isV) {
#pragma unroll
    for (int p = 0; p < 2; ++p) {
      int c = tid + p * 256;
      int row = c >> 3, c8 = c & 7;
      const float* sp = src + row * 64 + c8 * 8;
      float4 f0 = *(const float4*)sp;
      float4 f1 = *(const float4*)(sp + 4);
      uint4 u;
      u.x = cvt_pk_bf16(f0.x, f0.y);
      u.y = cvt_pk_bf16(f0.z, f0.w);
      u.z = cvt_pk_bf16(f1.x, f1.y);
      u.w = cvt_pk_bf16(f1.z, f1.w);
      *(uint4*)&dst[(row * 64 + c8 * 8) ^ ((row & 7) << 3)] = u;
    }
  } else {
    __shared__ float Vl[64][68];
    int row = tid >> 2, q4 = (tid & 3) * 16;
    const float* sp = src + row * 64 + q4;
#pragma unroll
    for (int i = 0; i < 4; ++i)
      *(float4*)&Vl[row][q4 + i * 4] = *(const float4*)(sp + i * 4);
    __syncthreads();
#pragma unroll
    for (int p = 0; p < 2; ++p) {
      int c = tid + p * 256;
      int d = c >> 3, kc = c & 7;
      float x[8];
#pragma unroll
      for (int j = 0; j < 8; ++j) x[j] = Vl[kc * 8 + j][d];
      uint4 u;
      u.x = cvt_pk_bf16(x[0], x[1]);
      u.y = cvt_pk_bf16(x[2], x[3]);
      u.z = cvt_pk_bf16(x[4], x[5]);
      u.w = cvt_pk_bf16(x[6], x[7]);
      *(uint4*)&dst[(d * 64 + kc * 8) ^ ((d & 7) << 3)] = u;
    }
  }
}

// ---------------------------------------------------------------------------
// Main flash-attention kernel, templated on KV-split count.
// Config: (512,6) bounds [FROZEN], SPLIT=2 (R10), Pl-LDS PV [the ONLY
// correct PV path — in-register MFMA16 miscomputes in non-spilled codegen,
// R6/R7/R11]. Single change vs R10: l-sum cross-lane reduction deferred to
// the epilogue (per-lane partial l_run in the loop; sum is linear and alpha
// is row-uniform, so this is a pure summation reorder).
// ---------------------------------------------------------------------------
template <int SPLIT>
__global__ __launch_bounds__(512, 6) void attn_main(
    const float* __restrict__ qg, const u16_t* __restrict__ kimg,
    const u16_t* __restrict__ vimg, float* __restrict__ outg,
    float* __restrict__ pacc, float* __restrict__ pml) {
  constexpr int TS = NT / SPLIT;
  __shared__ __align__(16) u16_t Kl[2][TILE_ELEMS];
  __shared__ __align__(16) u16_t Vt[2][TILE_ELEMS];
  __shared__ __align__(16) u16_t Pl[NW][16 * KB];

  const int tid = threadIdx.x;
  const int w = tid >> 6, l = tid & 63;
  const int g = l >> 4, qi = l & 15;

  // bijective XCD chunk swizzle: same-batch blocks stay on one XCD's L2
  constexpr int TOT = B_ * 16 * SPLIT;
  const int bidx = blockIdx.x;
  const int logical = (bidx & 7) * (TOT / 8) + (bidx >> 3);
  const int s  = logical & (SPLIT - 1);
  const int qt = (logical / SPLIT) & 15;
  const int b  = logical / (SPLIT * 16);
  const int q0 = qt * QB + w * 16;

  // ---- Q fragments, prescaled by (1/sqrt(64))*log2(e) for exp2 softmax ----
  short8 qf[2];
  {
    const float sc = 0.18033688011112042f;  // 0.125 * log2(e)
    const float* qp = qg + ((size_t)(b * N_ + q0 + qi)) * D_;
#pragma unroll
    for (int dc = 0; dc < 2; ++dc) {
      float4 f0 = *(const float4*)(qp + dc * 32 + g * 8);
      float4 f1 = *(const float4*)(qp + dc * 32 + g * 8 + 4);
      U8 u;
      u.u[0] = cvt_pk_bf16(f0.x * sc, f0.y * sc);
      u.u[1] = cvt_pk_bf16(f0.z * sc, f0.w * sc);
      u.u[2] = cvt_pk_bf16(f1.x * sc, f1.y * sc);
      u.u[3] = cvt_pk_bf16(f1.z * sc, f1.w * sc);
      qf[dc] = u.s8;
    }
  }

  f32x4 acc[4] = {{0,0,0,0},{0,0,0,0},{0,0,0,0},{0,0,0,0}};
  float m_run = -INFINITY;
  float l_run = 0.f;   // per-lane partial (16 of the row's 64 P values)

  const u16_t* kt = kimg + (size_t)b * NT * TILE_ELEMS;
  const u16_t* vt = vimg + (size_t)b * NT * TILE_ELEMS;

  auto stage = [&](int bb, int tt) {
    const u16_t* kp = kt + (size_t)tt * TILE_ELEMS + w * 512 + l * 8;
    const u16_t* vp = vt + (size_t)tt * TILE_ELEMS + w * 512 + l * 8;
    gload_lds16(kp, &Kl[bb][w * 512]);
    gload_lds16(vp, &Vt[bb][w * 512]);
  };

  const int t0 = s * TS;
  stage(0, t0);
  __syncthreads();

  for (int i = 0; i < TS; ++i) {
    const int cur = i & 1;
    if (i + 1 < TS) stage(cur ^ 1, t0 + i + 1);   // issue-early
    const u16_t* Kc = Kl[cur];
    const u16_t* Vc = Vt[cur];

    // ---- QK^T swapped: lane(g,qi) holds S[q=qi][kv=kvt*16+g*4+r] (log2 dom) ----
    f32x4 st[4];
    __builtin_amdgcn_s_setprio(1);
#pragma unroll
    for (int kvt = 0; kvt < 4; ++kvt) {
      int kvr = kvt * 16 + qi;
      int base = kvr * 64, sw = (kvr & 7) << 3;
      short8 kf0 = *(const short8*)&Kc[(base + g * 8) ^ sw];
      short8 kf1 = *(const short8*)&Kc[(base + 32 + g * 8) ^ sw];
      f32x4 z = {0, 0, 0, 0};
      z = __builtin_amdgcn_mfma_f32_16x16x32_bf16(kf0, qf[0], z, 0, 0, 0);
      z = __builtin_amdgcn_mfma_f32_16x16x32_bf16(kf1, qf[1], z, 0, 0, 0);
      st[kvt] = z;
    }
    __builtin_amdgcn_s_setprio(0);

    // ---- online softmax, exp2 domain, defer-max (THR=8) ----
    float m01 = fmaxf(fmaxf(st[0][0], st[0][1]), fmaxf(st[0][2], st[0][3]));
    float m23 = fmaxf(fmaxf(st[1][0], st[1][1]), fmaxf(st[1][2], st[1][3]));
    float m45 = fmaxf(fmaxf(st[2][0], st[2][1]), fmaxf(st[2][2], st[2][3]));
    float m67 = fmaxf(fmaxf(st[3][0], st[3][1]), fmaxf(st[3][2], st[3][3]));
    float mloc = fmaxf(fmaxf(m01, m23), fmaxf(m45, m67));
    mloc = fmaxf(mloc, __shfl_xor(mloc, 16));
    mloc = fmaxf(mloc, __shfl_xor(mloc, 32));
    if (__any(mloc > m_run + 8.0f)) {
      float mnew = fmaxf(m_run, mloc);
      float alpha = exp2_fast(m_run - mnew);   // row-uniform across g-lanes
      m_run = mnew;
      l_run *= alpha;
#pragma unroll
      for (int dt = 0; dt < 4; ++dt)
#pragma unroll
        for (int r = 0; r < 4; ++r) acc[dt][r] *= alpha;
    }
    float ps = 0.f;
#pragma unroll
    for (int kvt = 0; kvt < 4; ++kvt)
#pragma unroll
      for (int r = 0; r < 4; ++r) {
        float p = exp2_fast(st[kvt][r] - m_run);
        st[kvt][r] = p;
        ps += p;
      }
    l_run += ps;   // per-lane partial; cross-lane reduce deferred to epilogue

    // ---- pack P to bf16 via per-wave swizzled LDS (wave-internal) ----
#pragma unroll
    for (int kvt = 0; kvt < 4; ++kvt) {
      unsigned u0 = cvt_pk_bf16(st[kvt][0], st[kvt][1]);
      unsigned u1 = cvt_pk_bf16(st[kvt][2], st[kvt][3]);
      int kv = kvt * 16 + g * 4;
      int sw = (qi & 7) << 3;
      *(unsigned*)&Pl[w][(qi * 64 + kv) ^ sw]     = u0;
      *(unsigned*)&Pl[w][(qi * 64 + kv + 2) ^ sw] = u1;
    }
    asm volatile("s_waitcnt lgkmcnt(0)" ::: "memory");

    // ---- PV swapped: acc[dt][r] = O_partial[q=qi][d=dt*16+g*4+r] ----
    __builtin_amdgcn_s_setprio(1);
#pragma unroll
    for (int kk = 0; kk < 2; ++kk) {
      short8 pf = *(const short8*)&Pl[w][(qi * 64 + kk * 32 + g * 8) ^ ((qi & 7) << 3)];
#pragma unroll
      for (int dt = 0; dt < 4; ++dt) {
        int d = dt * 16 + qi;
        short8 vf = *(const short8*)&Vc[(d * 64 + kk * 32 + g * 8) ^ ((d & 7) << 3)];
        acc[dt] = __builtin_amdgcn_mfma_f32_16x16x32_bf16(vf, pf, acc[dt], 0, 0, 0);
      }
    }
    __builtin_amdgcn_s_setprio(0);
    __syncthreads();
  }

  // ---- epilogue: reduce l partials across the row's 4 g-lanes (once) ----
  l_run += __shfl_xor(l_run, 16);
  l_run += __shfl_xor(l_run, 32);

  const int wq = w * 16 + qi;
  if constexpr (SPLIT == 1) {
    float rl = 1.0f / l_run;
    float* op = outg + ((size_t)(b * N_ + qt * QB + wq)) * D_;
#pragma unroll
    for (int dt = 0; dt < 4; ++dt) {
      float4 o;
      o.x = acc[dt][0] * rl;
      o.y = acc[dt][1] * rl;
      o.z = acc[dt][2] * rl;
      o.w = acc[dt][3] * rl;
      *(float4*)(op + dt * 16 + g * 4) = o;
    }
  } else {
    const size_t rowid = (size_t)logical * QB + wq;
    float* ap = pacc + rowid * D_;
#pragma unroll
    for (int dt = 0; dt < 4; ++dt) {
      float4 o;
      o.x = acc[dt][0]; o.y = acc[dt][1]; o.z = acc[dt][2]; o.w = acc[dt][3];
      *(float4*)(ap + dt * 16 + g * 4) = o;
    }
    if (g == 0) *(float2*)&pml[rowid * 2] = make_float2(m_run, l_run);
  }
}

// ---------------------------------------------------------------------------
// Combine: merge SPLIT partials per q-row (log2-domain flash merge).
// ---------------------------------------------------------------------------
template <int SPLIT>
__global__ __launch_bounds__(256) void combine_kernel(
    const float* __restrict__ pacc, const float* __restrict__ pml,
    float* __restrict__ outg) {
  const int fid = blockIdx.x * 256 + threadIdx.x;
  const int q = fid >> 4;
  const int c = fid & 15;
  const int b = q >> 11, rem = q & 2047;
  const int qt = rem >> 7, wq = rem & 127;
  const size_t base = ((size_t)(b * 16 + qt) * SPLIT) * QB + wq;

  float m[SPLIT], lv[SPLIT];
#pragma unroll
  for (int s2 = 0; s2 < SPLIT; ++s2) {
    float2 ml = *(const float2*)&pml[(base + (size_t)s2 * QB) * 2];
    m[s2] = ml.x; lv[s2] = ml.y;
  }
  float ms = m[0];
#pragma unroll
  for (int s2 = 1; s2 < SPLIT; ++s2) ms = fmaxf(ms, m[s2]);
  float L = 0.f, wgt[SPLIT];
#pragma unroll
  for (int s2 = 0; s2 < SPLIT; ++s2) {
    wgt[s2] = exp2_fast(m[s2] - ms);
    L += wgt[s2] * lv[s2];
  }
  float rl = 1.0f / L;

  float4 o = {0.f, 0.f, 0.f, 0.f};
#pragma unroll
  for (int s2 = 0; s2 < SPLIT; ++s2) {
    float4 a = *(const float4*)&pacc[(base + (size_t)s2 * QB) * D_ + c * 4];
    o.x += wgt[s2] * a.x;
    o.y += wgt[s2] * a.y;
    o.z += wgt[s2] * a.z;
    o.w += wgt[s2] * a.w;
  }
  o.x *= rl; o.y *= rl; o.z *= rl; o.w *= rl;
  *(float4*)&outg[(size_t)fid * 4] = o;
}

// ---------------------------------------------------------------------------
// Fallback (known-good R2 kernel) if workspace is too small.
// ---------------------------------------------------------------------------
__global__ __launch_bounds__(512, 2) void attn_fwd_fallback(
    const float* __restrict__ qg, const float* __restrict__ kg,
    const float* __restrict__ vg, float* __restrict__ outg) {
  __shared__ __align__(16) u16_t Kl[KB * D_];
  __shared__ __align__(16) u16_t Vt[D_ * KB];
  __shared__ __align__(16) u16_t Pl[NW][16 * KB];

  const int tid = threadIdx.x;
  const int w = tid >> 6, l = tid & 63;
  const int g = l >> 4, qi = l & 15;
  const int bidx = blockIdx.x;
  const int b = bidx >> 4, qt = bidx & 15;
  const int q0 = qt * QB + w * 16;

  short8 qf[2];
  {
    const float* qp = qg + ((size_t)(b * N_ + q0 + qi)) * D_;
    const float sc = 0.125f;
#pragma unroll
    for (int dc = 0; dc < 2; ++dc) {
      float4 f0 = *(const float4*)(qp + dc * 32 + g * 8);
      float4 f1 = *(const float4*)(qp + dc * 32 + g * 8 + 4);
      U8 u;
      u.u[0] = cvt_pk_bf16(f0.x * sc, f0.y * sc);
      u.u[1] = cvt_pk_bf16(f0.z * sc, f0.w * sc);
      u.u[2] = cvt_pk_bf16(f1.x * sc, f1.y * sc);
      u.u[3] = cvt_pk_bf16(f1.z * sc, f1.w * sc);
      qf[dc] = u.s8;
    }
  }

  f32x4 acc[4] = {{0,0,0,0},{0,0,0,0},{0,0,0,0},{0,0,0,0}};
  float m_run = -INFINITY, l_run = 0.f;
  const float* kbase = kg + (size_t)b * N_ * D_;
  const float* vbase = vg + (size_t)b * N_ * D_;

  for (int kv0 = 0; kv0 < N_; kv0 += KB) {
#pragma unroll
    for (int p = 0; p < 2; ++p) {
      int idx = tid + p * 512;
      int row = idx >> 4, c4 = idx & 15;
      float4 f = *(const float4*)(kbase + (size_t)(kv0 + row) * D_ + c4 * 4);
      unsigned u0 = cvt_pk_bf16(f.x, f.y);
      unsigned u1 = cvt_pk_bf16(f.z, f.w);
      int o = (row * 64 + c4 * 4) ^ ((row & 7) << 3);
      *(uint2*)&Kl[o] = make_uint2(u0, u1);
    }
    {
      int rp = tid >> 4, c4 = tid & 15;
      int row2 = rp * 2;
      const float* vp = vbase + (size_t)(kv0 + row2) * D_ + c4 * 4;
      float4 a0 = *(const float4*)vp;
      float4 a1 = *(const float4*)(vp + D_);
      float lo[4] = {a0.x, a0.y, a0.z, a0.w};
      float hi[4] = {a1.x, a1.y, a1.z, a1.w};
#pragma unroll
      for (int i = 0; i < 4; ++i) {
        int d = c4 * 4 + i;
        unsigned u = cvt_pk_bf16(lo[i], hi[i]);
        int o = (d * 64 + row2) ^ ((d & 7) << 3);
        *(unsigned*)&Vt[o] = u;
      }
    }
    __syncthreads();

    f32x4 st[4];
#pragma unroll
    for (int kvt = 0; kvt < 4; ++kvt) {
      int kvr = kvt * 16 + qi;
      int base = kvr * 64, sw = (kvr & 7) << 3;
      short8 kf0 = *(const short8*)&Kl[(base + g * 8) ^ sw];
      short8 kf1 = *(const short8*)&Kl[(base + 32 + g * 8) ^ sw];
      f32x4 z = {0, 0, 0, 0};
      z = __builtin_amdgcn_mfma_f32_16x16x32_bf16(kf0, qf[0], z, 0, 0, 0);
      z = __builtin_amdgcn_mfma_f32_16x16x32_bf16(kf1, qf[1], z, 0, 0, 0);
      st[kvt] = z;
    }

    float mloc = -INFINITY;
#pragma unroll
    for (int kvt = 0; kvt < 4; ++kvt)
#pragma unroll
      for (int r = 0; r < 4; ++r) mloc = fmaxf(mloc, st[kvt][r]);
    mloc = fmaxf(mloc, __shfl_xor(mloc, 16));
    mloc = fmaxf(mloc, __shfl_xor(mloc, 32));
    float mnew = fmaxf(m_run, mloc);
    float alpha = __expf(m_run - mnew);
    m_run = mnew;

    float ps = 0.f;
#pragma unroll
    for (int kvt = 0; kvt < 4; ++kvt)
#pragma unroll
      for (int r = 0; r < 4; ++r) {
        float p = __expf(st[kvt][r] - mnew);
        st[kvt][r] = p;
        ps += p;
      }
    ps += __shfl_xor(ps, 16);
    ps += __shfl_xor(ps, 32);
    l_run = l_run * alpha + ps;

#pragma unroll
    for (int dt = 0; dt < 4; ++dt)
#pragma unroll
      for (int r = 0; r < 4; ++r) acc[dt][r] *= alpha;

#pragma unroll
    for (int kvt = 0; kvt < 4; ++kvt) {
      unsigned u0 = cvt_pk_bf16(st[kvt][0], st[kvt][1]);
      unsigned u1 = cvt_pk_bf16(st[kvt][2], st[kvt][3]);
      int kv = kvt * 16 + g * 4;
      int sw = (qi & 7) << 3;
      *(unsigned*)&Pl[w][(qi * 64 + kv) ^ sw]     = u0;
      *(unsigned*)&Pl[w][(qi * 64 + kv + 2) ^ sw] = u1;
    }
    asm volatile("s_waitcnt lgkmcnt(0)" ::: "memory");

#pragma unroll
    for (int kk = 0; kk < 2; ++kk) {
      short8 pf = *(const short8*)&Pl[w][(qi * 64 + kk * 32 + g * 8) ^ ((qi & 7) << 3)];
#pragma unroll
      for (int dt = 0; dt < 4; ++dt) {
        int d = dt * 16 + qi;
        short8 vf = *(const short8*)&Vt[(d * 64 + kk * 32 + g * 8) ^ ((d & 7) << 3)];
        acc[dt] = __builtin_amdgcn_mfma_f32_16x16x32_bf16(vf, pf, acc[dt], 0, 0, 0);
      }
    }
    __syncthreads();
  }

  float rl = 1.0f / l_run;
  float* op = outg + ((size_t)(b * N_ + q0 + qi)) * D_;
#pragma unroll
  for (int dt = 0; dt < 4; ++dt) {
    float4 o;
    o.x = acc[dt][0] * rl;
    o.y = acc[dt][1] * rl;
    o.z = acc[dt][2] * rl;
    o.w = acc[dt][3] * rl;
    *(float4*)(op + dt * 16 + g * 4) = o;
  }
}

extern "C" void kernel_launch(void* const* d_in, const int* in_sizes, int n_in,
                              void* d_out, int out_size, void* d_ws, size_t ws_size,
                              hipStream_t stream) {
  const float* q = (const float*)d_in[0];
  const float* k = (const float*)d_in[1];
  const float* v = (const float*)d_in[2];
  float* out = (float*)d_out;

  constexpr int SPLIT = 2;
  const size_t img_elems = (size_t)B_ * N_ * D_;            // 2M bf16 per image
  const size_t img_bytes = 2 * img_elems * sizeof(u16_t);   // 8 MB (K+V)
  const size_t rows = (size_t)B_ * N_ * SPLIT;              // partial rows
  const size_t acc_bytes = rows * D_ * sizeof(float);       // 16.8 MB
  const size_t ml_bytes = rows * 2 * sizeof(float);         // 0.5 MB
  const size_t need_split = img_bytes + acc_bytes + ml_bytes;

  if (ws_size >= need_split) {
    u16_t* kimg = (u16_t*)d_ws;
    u16_t* vimg = kimg + img_elems;
    float* pacc = (float*)((char*)d_ws + img_bytes);
    float* pml  = pacc + rows * D_;
    prep_kernel<<<dim3(B_ * NT * 2), dim3(256), 0, stream>>>(k, v, kimg, vimg);
    attn_main<SPLIT><<<dim3(B_ * 16 * SPLIT), dim3(512), 0, stream>>>(
        q, kimg, vimg, out, pacc, pml);
    combine_kernel<SPLIT><<<dim3((B_ * N_ * D_ / 4) / 256), dim3(256), 0, stream>>>(
        pacc, pml, out);
  } else if (ws_size >= img_bytes) {
    u16_t* kimg = (u16_t*)d_ws;
    u16_t* vimg = kimg + img_elems;
    prep_kernel<<<dim3(B_ * NT * 2), dim3(256), 0, stream>>>(k, v, kimg, vimg);
    attn_main<1><<<dim3(B_ * 16), dim3(512), 0, stream>>>(
        q, kimg, vimg, out, nullptr, nullptr);
  } else {
    attn_fwd_fallback<<<dim3(B_ * 16), dim3(512), 0, stream>>>(q, k, v, out);
  }
}